// Round 1
// 180.121 us; speedup vs baseline: 1.1919x; 1.1919x over previous
//
#include <hip/hip_runtime.h>

// Problem constants
#define NATOMS 20000
#define NCHAN  64
#define NIRR   16
#define K2 120
#define K1 8
#define K0 4

// ws layout (bytes):
//   [0 .. 524288)        W2bf  bf16[64][256][16]   c*4096 + xy*16 + i   (xy = x*16+y)
//   [524288 .. 557056)   W1bf  bf16[64][256]       c*256 + x*16 + y
//   [557056 .. 561152)   W0f   f32 [64][16]        c*16 + x
#define W1_BYTE_OFF 524288
#define W0_BYTE_OFF 557056

typedef __attribute__((ext_vector_type(8))) short bf16x8;
typedef __attribute__((ext_vector_type(4))) float f32x4;
typedef __attribute__((ext_vector_type(4))) unsigned int u32x4;

__device__ inline short f2bf(float f) {
    union { float f; unsigned u; } v; v.f = f;
    unsigned r = v.u + 0x7FFF + ((v.u >> 16) & 1);   // RNE
    return (short)(r >> 16);
}

// ---------------------------------------------------------------------------
// Kernel 1: fold weights.
// Blocks 0..255: LDS-tiled GEMM  [64 xyi rows x 120 k] @ [120 k x 16 c].
//   block b: xyi chunk = (b>>2)*64, c group = (b&3)*16.
//   Staging is fully coalesced; U2s padded to 121 floats/row so the
//   64-lane row-parallel read (stride 121, odd) is 2-way max (free).
// Blocks 256..263: W1bf (2048 outputs each).  Block 256 also does W0f.
// ---------------------------------------------------------------------------
__global__ __launch_bounds__(256) void precompute_kernel(
    const float* __restrict__ U2, const float* __restrict__ U1,
    const float* __restrict__ U0, const float* __restrict__ w2,
    const float* __restrict__ w1, const float* __restrict__ w0,
    void* __restrict__ wsv)
{
    short* W2bf = (short*)wsv;
    short* W1bf = (short*)((char*)wsv + W1_BYTE_OFF);
    float* W0f  = (float*)((char*)wsv + W0_BYTE_OFF);

    const int b = blockIdx.x;
    const int t = threadIdx.x;

    if (b < 256) {
        __shared__ __align__(16) float U2s[64][121];   // 30.9 KB
        __shared__ __align__(16) float w2s[120][16];   //  7.5 KB
        const int xyi0  = (b >> 2) * 64;
        const int cbase = (b & 3) * 16;

        // stage U2 rows [xyi0, xyi0+64) : 7680 floats, coalesced
        for (int o = t; o < 64 * 120; o += 256) {
            int r = o / 120, k = o - r * 120;
            U2s[r][k] = U2[(size_t)xyi0 * 120 + o];
        }
        // stage w2 columns [cbase, cbase+16) : 1920 floats
        for (int o = t; o < 120 * 16; o += 256) {
            int k = o >> 4, cc = o & 15;
            w2s[k][cc] = w2[k * NCHAN + cbase + cc];
        }
        __syncthreads();

        const int r = t & 63;       // row (lane)
        const int g = t >> 6;       // wave = c sub-group of 4
        float acc0 = 0.f, acc1 = 0.f, acc2 = 0.f, acc3 = 0.f;
        #pragma unroll 8
        for (int k = 0; k < 120; ++k) {
            float u = U2s[r][k];                          // 2-way max, free
            float4 w = *(const float4*)&w2s[k][g * 4];    // wave-uniform broadcast
            acc0 += u * w.x; acc1 += u * w.y; acc2 += u * w.z; acc3 += u * w.w;
        }
        const int xyi = xyi0 + r;
        const int cA  = cbase + g * 4;
        W2bf[(size_t)(cA + 0) * 4096 + xyi] = f2bf(acc0);  // lanes r consecutive:
        W2bf[(size_t)(cA + 1) * 4096 + xyi] = f2bf(acc1);  // 128B coalesced stores
        W2bf[(size_t)(cA + 2) * 4096 + xyi] = f2bf(acc2);
        W2bf[(size_t)(cA + 3) * 4096 + xyi] = f2bf(acc3);
    } else {
        const int lb = b - 256;                // 0..7
        for (int o = t; o < 2048; o += 256) {
            int go = lb * 2048 + o;            // 0..16383
            int c = go >> 8, xy = go & 255;
            const float* u = U1 + xy * K1;
            float acc = 0.f;
            #pragma unroll
            for (int k = 0; k < K1; ++k) acc += u[k] * w1[k * NCHAN + c];
            W1bf[c * 256 + xy] = f2bf(acc);
        }
        if (lb == 0) {
            for (int o = t; o < 1024; o += 256) {
                int c = o >> 4, x = o & 15;
                const float* u = U0 + x * K0;
                float acc = 0.f;
                #pragma unroll
                for (int k = 0; k < K0; ++k) acc += u[k] * w0[k * NCHAN + c];
                W0f[c * 16 + x] = acc;
            }
        }
    }
}

// ---------------------------------------------------------------------------
// Kernel 2: fused contraction, ZERO LDS, transposed MFMA.
//   Block = 256 thr = 4 waves = 4 consecutive channels; each wave loops over
//   10 atom tiles of 16 atoms (grid.y chunk of 160 atoms).
//   Per MFMA j (=x):  D = A x B  with
//     A[row=y][k] : k<16 -> W2bf[c][x*16+y][k] ; k=16 -> bf16(C1[x,y]); else 0
//     B[k][col=a] : k<16 -> bf16(f[a][k])      ; k=16 -> 1.0          ; else 0
//   => D[y][a] = M[x,y] for atom a  (M = A2 + C1), verified layouts (m89):
//     A: lane(q,m) elem e -> A[m][q*8+e];  B: lane(q,m) elem e -> B[q*8+e][m]
//     D: lane(q,m) reg  r -> D[q*4+r][m]
//   Lane (q,m) owns atom m, y-slots q*4..q*4+3: the whole epilogue
//     sy[r] = sum_x f[x]*M[x,y] ;  s = sum_r f[y]*(sy[r]+C0[y])
//   is lane-local fp32 (lane holds its atom's full f[16]); reduce over the
//   4 q-groups with 2 shfl_xor.  W2/C1 fragments live in 64 VGPRs for the
//   whole block (atom-independent); f double-buffered one tile ahead.
// ---------------------------------------------------------------------------
__device__ __forceinline__ void compute_tile(
    const bf16x8 (&aw)[16], float4 c0, int q,
    float4 va, float4 vb, float4 vc, float4 vd,
    float* __restrict__ outp)
{
    float f0 = va.x, f1 = va.y, f2 = va.z, f3 = va.w;
    float f4 = vb.x, f5 = vb.y, f6 = vb.z, f7 = vb.w;
    float f8 = vc.x, f9 = vc.y, f10 = vc.z, f11 = vc.w;
    float f12 = vd.x, f13 = vd.y, f14 = vd.z, f15 = vd.w;

    unsigned pk0, pk1, pk2, pk3, pk4, pk5, pk6, pk7;
    asm("v_cvt_pk_bf16_f32 %0, %1, %2" : "=v"(pk0) : "v"(f0),  "v"(f1));
    asm("v_cvt_pk_bf16_f32 %0, %1, %2" : "=v"(pk1) : "v"(f2),  "v"(f3));
    asm("v_cvt_pk_bf16_f32 %0, %1, %2" : "=v"(pk2) : "v"(f4),  "v"(f5));
    asm("v_cvt_pk_bf16_f32 %0, %1, %2" : "=v"(pk3) : "v"(f6),  "v"(f7));
    asm("v_cvt_pk_bf16_f32 %0, %1, %2" : "=v"(pk4) : "v"(f8),  "v"(f9));
    asm("v_cvt_pk_bf16_f32 %0, %1, %2" : "=v"(pk5) : "v"(f10), "v"(f11));
    asm("v_cvt_pk_bf16_f32 %0, %1, %2" : "=v"(pk6) : "v"(f12), "v"(f13));
    asm("v_cvt_pk_bf16_f32 %0, %1, %2" : "=v"(pk7) : "v"(f14), "v"(f15));

    // B-fragment select by q: q0 -> k 0..7, q1 -> k 8..15, q2 -> {1.0,0..}, q3 -> 0
    unsigned w0s = (q == 0) ? pk0 : (q == 1) ? pk4 : (q == 2) ? 0x00003f80u : 0u;
    unsigned w1s = (q == 0) ? pk1 : (q == 1) ? pk5 : 0u;
    unsigned w2s_ = (q == 0) ? pk2 : (q == 1) ? pk6 : 0u;
    unsigned w3s = (q == 0) ? pk3 : (q == 1) ? pk7 : 0u;
    u32x4 bu = {w0s, w1s, w2s_, w3s};
    bf16x8 bfr = __builtin_bit_cast(bf16x8, bu);

    const f32x4 z = {0.f, 0.f, 0.f, 0.f};
    f32x4 sy = z;
    f32x4 d0 = __builtin_amdgcn_mfma_f32_16x16x32_bf16(aw[0], bfr, z, 0, 0, 0);
    f32x4 d1 = __builtin_amdgcn_mfma_f32_16x16x32_bf16(aw[1], bfr, z, 0, 0, 0);
    f32x4 d2 = __builtin_amdgcn_mfma_f32_16x16x32_bf16(aw[2], bfr, z, 0, 0, 0);
    f32x4 d3 = __builtin_amdgcn_mfma_f32_16x16x32_bf16(aw[3], bfr, z, 0, 0, 0);
    sy += d0 * f0;  d0 = __builtin_amdgcn_mfma_f32_16x16x32_bf16(aw[4],  bfr, z, 0, 0, 0);
    sy += d1 * f1;  d1 = __builtin_amdgcn_mfma_f32_16x16x32_bf16(aw[5],  bfr, z, 0, 0, 0);
    sy += d2 * f2;  d2 = __builtin_amdgcn_mfma_f32_16x16x32_bf16(aw[6],  bfr, z, 0, 0, 0);
    sy += d3 * f3;  d3 = __builtin_amdgcn_mfma_f32_16x16x32_bf16(aw[7],  bfr, z, 0, 0, 0);
    sy += d0 * f4;  d0 = __builtin_amdgcn_mfma_f32_16x16x32_bf16(aw[8],  bfr, z, 0, 0, 0);
    sy += d1 * f5;  d1 = __builtin_amdgcn_mfma_f32_16x16x32_bf16(aw[9],  bfr, z, 0, 0, 0);
    sy += d2 * f6;  d2 = __builtin_amdgcn_mfma_f32_16x16x32_bf16(aw[10], bfr, z, 0, 0, 0);
    sy += d3 * f7;  d3 = __builtin_amdgcn_mfma_f32_16x16x32_bf16(aw[11], bfr, z, 0, 0, 0);
    sy += d0 * f8;  d0 = __builtin_amdgcn_mfma_f32_16x16x32_bf16(aw[12], bfr, z, 0, 0, 0);
    sy += d1 * f9;  d1 = __builtin_amdgcn_mfma_f32_16x16x32_bf16(aw[13], bfr, z, 0, 0, 0);
    sy += d2 * f10; d2 = __builtin_amdgcn_mfma_f32_16x16x32_bf16(aw[14], bfr, z, 0, 0, 0);
    sy += d3 * f11; d3 = __builtin_amdgcn_mfma_f32_16x16x32_bf16(aw[15], bfr, z, 0, 0, 0);
    sy += d0 * f12; sy += d1 * f13; sy += d2 * f14; sy += d3 * f15;

    // fy[r] = f[q*4+r] via cndmask (no dynamic register indexing)
    float t0 = (q & 1) ? f4 : f0;   float u0 = (q & 1) ? f12 : f8;
    float fy0 = (q & 2) ? u0 : t0;
    float t1 = (q & 1) ? f5 : f1;   float u1 = (q & 1) ? f13 : f9;
    float fy1 = (q & 2) ? u1 : t1;
    float t2 = (q & 1) ? f6 : f2;   float u2 = (q & 1) ? f14 : f10;
    float fy2 = (q & 2) ? u2 : t2;
    float t3 = (q & 1) ? f7 : f3;   float u3 = (q & 1) ? f15 : f11;
    float fy3 = (q & 2) ? u3 : t3;

    float s = fy0 * (sy.x + c0.x);
    s = fmaf(fy1, sy.y + c0.y, s);
    s = fmaf(fy2, sy.z + c0.z, s);
    s = fmaf(fy3, sy.w + c0.w, s);
    s += __shfl_xor(s, 16);
    s += __shfl_xor(s, 32);
    if (q == 0) *outp = s;
}

__global__ __launch_bounds__(256, 3) void contract_kernel(
    const float* __restrict__ nf,   // [N, 64, 16]
    const void* __restrict__ wsv,
    float* __restrict__ out)        // [N, 64]
{
    const short* W2g = (const short*)wsv;
    const short* W1g = (const short*)((const char*)wsv + W1_BYTE_OFF);
    const float* W0g = (const float*)((const char*)wsv + W0_BYTE_OFF);

    const int tid  = threadIdx.x;
    const int wave = tid >> 6;
    const int lane = tid & 63;
    const int m    = lane & 15;     // atom-within-tile / A-row / D-col
    const int q    = lane >> 4;     // quad: k-half (A/B), y-group (D)
    const int c    = blockIdx.x * 4 + wave;   // c fastest in grid -> write locality
    const int chunk = blockIdx.y;   // atoms [chunk*160, chunk*160+160)

    // A-operand fragments (W2 + C1 in K-slot 16), resident in VGPRs all block
    bf16x8 aw[16];
    #pragma unroll
    for (int j = 0; j < 16; ++j) {
        bf16x8 v = (bf16x8)0;
        if (q < 2) {
            v = *(const bf16x8*)(W2g + ((size_t)c << 12) + ((j * 16 + m) << 4) + (q << 3));
        } else if (q == 2) {
            v[0] = W1g[(c << 8) + (j << 4) + m];   // bf16(C1[x=j][y=m]) at k=16
        }
        aw[j] = v;
    }
    const float4 c0 = *(const float4*)(W0g + (c << 4) + (q << 2));  // C0[q*4..q*4+3]

    const float* fbase = nf + ((size_t)chunk * 160 + m) * 1024 + c * 16;
    float* obase = out + ((size_t)chunk * 160 + m) * 64 + c;

    float4 a0, a1, a2, a3, e0, e1, e2, e3;
    {   // prologue: tile 0
        const float4* p = (const float4*)fbase;
        a0 = p[0]; a1 = p[1]; a2 = p[2]; a3 = p[3];
    }
    for (int T = 0; T < 10; T += 2) {
        {   // prefetch tile T+1
            const float4* p = (const float4*)(fbase + (size_t)(T + 1) * 16384);
            e0 = p[0]; e1 = p[1]; e2 = p[2]; e3 = p[3];
        }
        compute_tile(aw, c0, q, a0, a1, a2, a3, obase + (size_t)T * 1024);
        {   // prefetch tile T+2 (clamped: last one redundantly reloads tile 0)
            int Tn = (T + 2 < 10) ? (T + 2) : 0;
            const float4* p = (const float4*)(fbase + (size_t)Tn * 16384);
            a0 = p[0]; a1 = p[1]; a2 = p[2]; a3 = p[3];
        }
        compute_tile(aw, c0, q, e0, e1, e2, e3, obase + (size_t)(T + 1) * 1024);
    }
}

extern "C" void kernel_launch(void* const* d_in, const int* in_sizes, int n_in,
                              void* d_out, int out_size, void* d_ws, size_t ws_size,
                              hipStream_t stream)
{
    const float* nf = (const float*)d_in[0];
    const float* U2 = (const float*)d_in[1];
    const float* U1 = (const float*)d_in[2];
    const float* U0 = (const float*)d_in[3];
    const float* w2 = (const float*)d_in[4];
    const float* w1 = (const float*)d_in[5];
    const float* w0 = (const float*)d_in[6];
    float* out = (float*)d_out;

    precompute_kernel<<<264, 256, 0, stream>>>(U2, U1, U0, w2, w1, w0, d_ws);

    dim3 grid(16, 125);   // x = c-group (fastest, write-line locality), y = atom chunk
    contract_kernel<<<grid, 256, 0, stream>>>(nf, d_ws, out);
}

// Round 2
// 176.168 us; speedup vs baseline: 1.2187x; 1.0224x over previous
//
#include <hip/hip_runtime.h>

// Problem constants
#define NATOMS 20000
#define NCHAN  64
#define NIRR   16
#define K2 120
#define K1 8
#define K0 4

// ws layout (bytes):
//   [0 .. 524288)        W2bf  bf16[64][256][16]   c*4096 + xy*16 + i   (xy = x*16+y)
//   [524288 .. 557056)   W1bf  bf16[64][256]       c*256 + x*16 + y
//   [557056 .. 561152)   W0f   f32 [64][16]        c*16 + x
#define W1_BYTE_OFF 524288
#define W0_BYTE_OFF 557056

#define NT 10              // atom tiles per block (16 atoms each -> 160 atoms/block)

typedef __attribute__((ext_vector_type(8))) short bf16x8;
typedef __attribute__((ext_vector_type(4))) float f32x4;
typedef __attribute__((ext_vector_type(4))) unsigned int u32x4;

__device__ inline short f2bf(float f) {
    union { float f; unsigned u; } v; v.f = f;
    unsigned r = v.u + 0x7FFF + ((v.u >> 16) & 1);   // RNE
    return (short)(r >> 16);
}

// ---------------------------------------------------------------------------
// Kernel 1: fold weights (unchanged from previous round — ~5-10 us).
// ---------------------------------------------------------------------------
__global__ __launch_bounds__(256) void precompute_kernel(
    const float* __restrict__ U2, const float* __restrict__ U1,
    const float* __restrict__ U0, const float* __restrict__ w2,
    const float* __restrict__ w1, const float* __restrict__ w0,
    void* __restrict__ wsv)
{
    short* W2bf = (short*)wsv;
    short* W1bf = (short*)((char*)wsv + W1_BYTE_OFF);
    float* W0f  = (float*)((char*)wsv + W0_BYTE_OFF);

    const int b = blockIdx.x;
    const int t = threadIdx.x;

    if (b < 256) {
        __shared__ __align__(16) float U2s[64][121];   // 30.9 KB
        __shared__ __align__(16) float w2s[120][16];   //  7.5 KB
        const int xyi0  = (b >> 2) * 64;
        const int cbase = (b & 3) * 16;

        for (int o = t; o < 64 * 120; o += 256) {
            int r = o / 120, k = o - r * 120;
            U2s[r][k] = U2[(size_t)xyi0 * 120 + o];
        }
        for (int o = t; o < 120 * 16; o += 256) {
            int k = o >> 4, cc = o & 15;
            w2s[k][cc] = w2[k * NCHAN + cbase + cc];
        }
        __syncthreads();

        const int r = t & 63;       // row (lane)
        const int g = t >> 6;       // wave = c sub-group of 4
        float acc0 = 0.f, acc1 = 0.f, acc2 = 0.f, acc3 = 0.f;
        #pragma unroll 8
        for (int k = 0; k < 120; ++k) {
            float u = U2s[r][k];                          // 2-way max, free
            float4 w = *(const float4*)&w2s[k][g * 4];    // wave-uniform broadcast
            acc0 += u * w.x; acc1 += u * w.y; acc2 += u * w.z; acc3 += u * w.w;
        }
        const int xyi = xyi0 + r;
        const int cA  = cbase + g * 4;
        W2bf[(size_t)(cA + 0) * 4096 + xyi] = f2bf(acc0);
        W2bf[(size_t)(cA + 1) * 4096 + xyi] = f2bf(acc1);
        W2bf[(size_t)(cA + 2) * 4096 + xyi] = f2bf(acc2);
        W2bf[(size_t)(cA + 3) * 4096 + xyi] = f2bf(acc3);
    } else {
        const int lb = b - 256;                // 0..7
        for (int o = t; o < 2048; o += 256) {
            int go = lb * 2048 + o;
            int c = go >> 8, xy = go & 255;
            const float* u = U1 + xy * K1;
            float acc = 0.f;
            #pragma unroll
            for (int k = 0; k < K1; ++k) acc += u[k] * w1[k * NCHAN + c];
            W1bf[c * 256 + xy] = f2bf(acc);
        }
        if (lb == 0) {
            for (int o = t; o < 1024; o += 256) {
                int c = o >> 4, x = o & 15;
                const float* u = U0 + x * K0;
                float acc = 0.f;
                #pragma unroll
                for (int k = 0; k < K0; ++k) acc += u[k] * w0[k * NCHAN + c];
                W0f[c * 16 + x] = acc;
            }
        }
    }
}

// ---------------------------------------------------------------------------
// global -> LDS async copy, 16 B per lane (dest = wave-uniform base + lane*16)
// ---------------------------------------------------------------------------
__device__ __forceinline__ void gload_lds16(const void* g, void* l) {
    __builtin_amdgcn_global_load_lds(
        (const __attribute__((address_space(1))) unsigned int*)g,
        (__attribute__((address_space(3))) unsigned int*)l, 16, 0, 0);
}

// ---------------------------------------------------------------------------
// Per-tile math (identical verified MFMA structure as previous round):
//   A[y][k]: k<16 -> W2bf[c][x*16+y][k]; k=16 -> bf16(C1[x,y]); else 0
//   B[k][a]: k<16 -> bf16(f[a][k]);      k=16 -> 1.0;           else 0
//   D[y][a] = M[x,y] (= A2 + C1);  lane (q,m) owns atom m, y-rows q*4..q*4+3.
//   s = sum_y f[y]*(sum_x f[x]*M[x,y] + C0[y]), reduced over q by 2 shfl_xor.
// ---------------------------------------------------------------------------
__device__ __forceinline__ float compute_tile(
    const bf16x8 (&aw)[16], float4 c0, int q,
    float4 va, float4 vb, float4 vc, float4 vd)
{
    float f0 = va.x, f1 = va.y, f2 = va.z, f3 = va.w;
    float f4 = vb.x, f5 = vb.y, f6 = vb.z, f7 = vb.w;
    float f8 = vc.x, f9 = vc.y, f10 = vc.z, f11 = vc.w;
    float f12 = vd.x, f13 = vd.y, f14 = vd.z, f15 = vd.w;

    unsigned pk0, pk1, pk2, pk3, pk4, pk5, pk6, pk7;
    asm("v_cvt_pk_bf16_f32 %0, %1, %2" : "=v"(pk0) : "v"(f0),  "v"(f1));
    asm("v_cvt_pk_bf16_f32 %0, %1, %2" : "=v"(pk1) : "v"(f2),  "v"(f3));
    asm("v_cvt_pk_bf16_f32 %0, %1, %2" : "=v"(pk2) : "v"(f4),  "v"(f5));
    asm("v_cvt_pk_bf16_f32 %0, %1, %2" : "=v"(pk3) : "v"(f6),  "v"(f7));
    asm("v_cvt_pk_bf16_f32 %0, %1, %2" : "=v"(pk4) : "v"(f8),  "v"(f9));
    asm("v_cvt_pk_bf16_f32 %0, %1, %2" : "=v"(pk5) : "v"(f10), "v"(f11));
    asm("v_cvt_pk_bf16_f32 %0, %1, %2" : "=v"(pk6) : "v"(f12), "v"(f13));
    asm("v_cvt_pk_bf16_f32 %0, %1, %2" : "=v"(pk7) : "v"(f14), "v"(f15));

    unsigned w0s = (q == 0) ? pk0 : (q == 1) ? pk4 : (q == 2) ? 0x00003f80u : 0u;
    unsigned w1s = (q == 0) ? pk1 : (q == 1) ? pk5 : 0u;
    unsigned w2s_ = (q == 0) ? pk2 : (q == 1) ? pk6 : 0u;
    unsigned w3s = (q == 0) ? pk3 : (q == 1) ? pk7 : 0u;
    u32x4 bu = {w0s, w1s, w2s_, w3s};
    bf16x8 bfr = __builtin_bit_cast(bf16x8, bu);

    const f32x4 z = {0.f, 0.f, 0.f, 0.f};
    f32x4 sy = z;
    f32x4 d0 = __builtin_amdgcn_mfma_f32_16x16x32_bf16(aw[0], bfr, z, 0, 0, 0);
    f32x4 d1 = __builtin_amdgcn_mfma_f32_16x16x32_bf16(aw[1], bfr, z, 0, 0, 0);
    f32x4 d2 = __builtin_amdgcn_mfma_f32_16x16x32_bf16(aw[2], bfr, z, 0, 0, 0);
    f32x4 d3 = __builtin_amdgcn_mfma_f32_16x16x32_bf16(aw[3], bfr, z, 0, 0, 0);
    sy += d0 * f0;  d0 = __builtin_amdgcn_mfma_f32_16x16x32_bf16(aw[4],  bfr, z, 0, 0, 0);
    sy += d1 * f1;  d1 = __builtin_amdgcn_mfma_f32_16x16x32_bf16(aw[5],  bfr, z, 0, 0, 0);
    sy += d2 * f2;  d2 = __builtin_amdgcn_mfma_f32_16x16x32_bf16(aw[6],  bfr, z, 0, 0, 0);
    sy += d3 * f3;  d3 = __builtin_amdgcn_mfma_f32_16x16x32_bf16(aw[7],  bfr, z, 0, 0, 0);
    sy += d0 * f4;  d0 = __builtin_amdgcn_mfma_f32_16x16x32_bf16(aw[8],  bfr, z, 0, 0, 0);
    sy += d1 * f5;  d1 = __builtin_amdgcn_mfma_f32_16x16x32_bf16(aw[9],  bfr, z, 0, 0, 0);
    sy += d2 * f6;  d2 = __builtin_amdgcn_mfma_f32_16x16x32_bf16(aw[10], bfr, z, 0, 0, 0);
    sy += d3 * f7;  d3 = __builtin_amdgcn_mfma_f32_16x16x32_bf16(aw[11], bfr, z, 0, 0, 0);
    sy += d0 * f8;  d0 = __builtin_amdgcn_mfma_f32_16x16x32_bf16(aw[12], bfr, z, 0, 0, 0);
    sy += d1 * f9;  d1 = __builtin_amdgcn_mfma_f32_16x16x32_bf16(aw[13], bfr, z, 0, 0, 0);
    sy += d2 * f10; d2 = __builtin_amdgcn_mfma_f32_16x16x32_bf16(aw[14], bfr, z, 0, 0, 0);
    sy += d3 * f11; d3 = __builtin_amdgcn_mfma_f32_16x16x32_bf16(aw[15], bfr, z, 0, 0, 0);
    sy += d0 * f12; sy += d1 * f13; sy += d2 * f14; sy += d3 * f15;

    float t0 = (q & 1) ? f4 : f0;   float u0 = (q & 1) ? f12 : f8;
    float fy0 = (q & 2) ? u0 : t0;
    float t1 = (q & 1) ? f5 : f1;   float u1 = (q & 1) ? f13 : f9;
    float fy1 = (q & 2) ? u1 : t1;
    float t2 = (q & 1) ? f6 : f2;   float u2 = (q & 1) ? f14 : f10;
    float fy2 = (q & 2) ? u2 : t2;
    float t3 = (q & 1) ? f7 : f3;   float u3 = (q & 1) ? f15 : f11;
    float fy3 = (q & 2) ? u3 : t3;

    float s = fy0 * (sy.x + c0.x);
    s = fmaf(fy1, sy.y + c0.y, s);
    s = fmaf(fy2, sy.z + c0.z, s);
    s = fmaf(fy3, sy.w + c0.w, s);
    s += __shfl_xor(s, 16);
    s += __shfl_xor(s, 32);
    return s;
}

// ---------------------------------------------------------------------------
// Kernel 2: fused contraction with coalesced LDS staging.
//   Block = 512 thr = 8 waves = 8 consecutive channels (c = bx*8 + wave);
//   tile = 16 atoms. Per tile: 16 atoms x 512 B (this block's 8-channel slab,
//   contiguous in nf) staged via ONE global_load_lds_dwordx4 per wave
//   (linear LDS dest, inverse-XOR-swizzled global source: T21 both-sides rule).
//   Read side: lane (q,m) does 4x ds_read_b128 of atom m's 16 floats at
//   byte (m*512 + ((wave*64 + r*16) ^ ((m&7)<<4))): 8 disjoint 4-bank groups,
//   2-way (m vs m+8) = free; q-duplicates are same-address broadcast.
//   Double-buffered, counted s_waitcnt vmcnt(1) keeps next stage in flight
//   across the barrier (no stores in loop: outputs accumulate in 10 regs).
// ---------------------------------------------------------------------------
__global__ __launch_bounds__(512, 3) void contract_kernel(
    const float* __restrict__ nf,   // [N, 64, 16]
    const void* __restrict__ wsv,
    float* __restrict__ out)        // [N, 64]
{
    __shared__ __align__(16) float fs[2][2048];   // 2 x 8 KB tile buffers

    const short* W2g = (const short*)wsv;
    const short* W1g = (const short*)((const char*)wsv + W1_BYTE_OFF);
    const float* W0g = (const float*)((const char*)wsv + W0_BYTE_OFF);

    const int tid  = threadIdx.x;
    const int wave = tid >> 6;      // 0..7 = channel-within-group
    const int lane = tid & 63;
    const int m    = lane & 15;     // atom-within-tile
    const int q    = lane >> 4;
    const int c    = blockIdx.x * 8 + wave;
    const int chunk = blockIdx.y;   // atoms [chunk*160, chunk*160+160)

    // --- staging addresses ---
    const int a_st = tid >> 5;                       // atom 0..15 this lane stages
    const int soff = ((tid & 31) << 4) ^ ((a_st & 7) << 4);  // inverse swizzle
    const char* sbase = (const char*)nf
        + ((size_t)(chunk * 160 + a_st) << 12)       // atom * 4096 B
        + ((size_t)blockIdx.x << 9)                  // channel-group * 512 B
        + soff;
    char* ldst0 = (char*)&fs[0][0] + (wave << 10);   // wave-uniform dest
    char* ldst1 = (char*)&fs[1][0] + (wave << 10);

    // --- A-operand fragments (W2 + C1 in K-slot 16), resident in VGPRs ---
    bf16x8 aw[16];
    #pragma unroll
    for (int j = 0; j < 16; ++j) {
        bf16x8 v = (bf16x8)0;
        if (q < 2) {
            v = *(const bf16x8*)(W2g + ((size_t)c << 12) + ((j * 16 + m) << 4) + (q << 3));
        } else if (q == 2) {
            v[0] = W1g[(c << 8) + (j << 4) + m];
        }
        aw[j] = v;
    }
    const float4 c0 = *(const float4*)(W0g + (c << 4) + (q << 2));

    // --- LDS read base (swizzled) ---
    const unsigned sw = (unsigned)((m & 7) << 4);
    const unsigned zb = (unsigned)(wave << 6);

    float outv[NT];

    // prologue: stage tile 0 into buffer 0
    gload_lds16(sbase, ldst0);

    #pragma unroll
    for (int T = 0; T < NT; ++T) {
        const int b = T & 1;
        if (T + 1 < NT)
            gload_lds16(sbase + (size_t)(T + 1) * 65536, b ? ldst0 : ldst1);
        if (T + 1 < NT) { asm volatile("s_waitcnt vmcnt(1)" ::: "memory"); }
        else            { asm volatile("s_waitcnt vmcnt(0)" ::: "memory"); }
        __builtin_amdgcn_s_barrier();

        const char* lrb = (const char*)&fs[b][0] + (m << 9);
        float4 va = *(const float4*)(lrb + ((zb +  0) ^ sw));
        float4 vb = *(const float4*)(lrb + ((zb + 16) ^ sw));
        float4 vc = *(const float4*)(lrb + ((zb + 32) ^ sw));
        float4 vd = *(const float4*)(lrb + ((zb + 48) ^ sw));

        outv[T] = compute_tile(aw, c0, q, va, vb, vc, vd);

        __builtin_amdgcn_s_barrier();   // readers done before next overwrite
    }

    if (q == 0) {
        float* ob = out + ((size_t)(chunk * 160 + m)) * 64 + c;
        #pragma unroll
        for (int T = 0; T < NT; ++T)
            ob[(size_t)T * 1024] = outv[T];   // atom += 16 -> +1024 floats
    }
}

extern "C" void kernel_launch(void* const* d_in, const int* in_sizes, int n_in,
                              void* d_out, int out_size, void* d_ws, size_t ws_size,
                              hipStream_t stream)
{
    const float* nf = (const float*)d_in[0];
    const float* U2 = (const float*)d_in[1];
    const float* U1 = (const float*)d_in[2];
    const float* U0 = (const float*)d_in[3];
    const float* w2 = (const float*)d_in[4];
    const float* w1 = (const float*)d_in[5];
    const float* w0 = (const float*)d_in[6];
    float* out = (float*)d_out;

    precompute_kernel<<<264, 256, 0, stream>>>(U2, U1, U0, w2, w1, w0, d_ws);

    dim3 grid(8, 125);   // x = channel group of 8, y = atom chunk of 160
    contract_kernel<<<grid, 512, 0, stream>>>(nf, d_ws, out);
}

// Round 3
// 160.870 us; speedup vs baseline: 1.3346x; 1.0951x over previous
//
#include <hip/hip_runtime.h>

// Problem constants
#define NATOMS 20000
#define NCHAN  64
#define NIRR   16
#define K2 120
#define K1 8
#define K0 4

// ws layout (bytes):
//   [0 .. 524288)        W2bf  bf16[64][256][16]   c*4096 + xy*16 + i   (xy = x*16+y)
//   [524288 .. 557056)   W1bf  bf16[64][256]       c*256 + x*16 + y
//   [557056 .. 561152)   W0f   f32 [64][16]        c*16 + x
#define W1_BYTE_OFF 524288
#define W0_BYTE_OFF 557056

#define NT 10              // atom tiles per block (16 atoms each -> 160 atoms)
#define DEPTH 3            // prefetch distance (4 LDS buffers)

typedef __attribute__((ext_vector_type(8))) short bf16x8;
typedef __attribute__((ext_vector_type(4))) float f32x4;
typedef __attribute__((ext_vector_type(4))) unsigned int u32x4;

__device__ inline short f2bf(float f) {
    union { float f; unsigned u; } v; v.f = f;
    unsigned r = v.u + 0x7FFF + ((v.u >> 16) & 1);   // RNE
    return (short)(r >> 16);
}

// ---------------------------------------------------------------------------
// Kernel 1: fold weights (unchanged — tiled GEMM, ~5-10 us).
// ---------------------------------------------------------------------------
__global__ __launch_bounds__(256) void precompute_kernel(
    const float* __restrict__ U2, const float* __restrict__ U1,
    const float* __restrict__ U0, const float* __restrict__ w2,
    const float* __restrict__ w1, const float* __restrict__ w0,
    void* __restrict__ wsv)
{
    short* W2bf = (short*)wsv;
    short* W1bf = (short*)((char*)wsv + W1_BYTE_OFF);
    float* W0f  = (float*)((char*)wsv + W0_BYTE_OFF);

    const int b = blockIdx.x;
    const int t = threadIdx.x;

    if (b < 256) {
        __shared__ __align__(16) float U2s[64][121];   // 30.9 KB
        __shared__ __align__(16) float w2s[120][16];   //  7.5 KB
        const int xyi0  = (b >> 2) * 64;
        const int cbase = (b & 3) * 16;

        for (int o = t; o < 64 * 120; o += 256) {
            int r = o / 120, k = o - r * 120;
            U2s[r][k] = U2[(size_t)xyi0 * 120 + o];
        }
        for (int o = t; o < 120 * 16; o += 256) {
            int k = o >> 4, cc = o & 15;
            w2s[k][cc] = w2[k * NCHAN + cbase + cc];
        }
        __syncthreads();

        const int r = t & 63;       // row (lane)
        const int g = t >> 6;       // wave = c sub-group of 4
        float acc0 = 0.f, acc1 = 0.f, acc2 = 0.f, acc3 = 0.f;
        #pragma unroll 8
        for (int k = 0; k < 120; ++k) {
            float u = U2s[r][k];                          // 2-way max, free
            float4 w = *(const float4*)&w2s[k][g * 4];    // wave-uniform broadcast
            acc0 += u * w.x; acc1 += u * w.y; acc2 += u * w.z; acc3 += u * w.w;
        }
        const int xyi = xyi0 + r;
        const int cA  = cbase + g * 4;
        W2bf[(size_t)(cA + 0) * 4096 + xyi] = f2bf(acc0);
        W2bf[(size_t)(cA + 1) * 4096 + xyi] = f2bf(acc1);
        W2bf[(size_t)(cA + 2) * 4096 + xyi] = f2bf(acc2);
        W2bf[(size_t)(cA + 3) * 4096 + xyi] = f2bf(acc3);
    } else {
        const int lb = b - 256;                // 0..7
        for (int o = t; o < 2048; o += 256) {
            int go = lb * 2048 + o;
            int c = go >> 8, xy = go & 255;
            const float* u = U1 + xy * K1;
            float acc = 0.f;
            #pragma unroll
            for (int k = 0; k < K1; ++k) acc += u[k] * w1[k * NCHAN + c];
            W1bf[c * 256 + xy] = f2bf(acc);
        }
        if (lb == 0) {
            for (int o = t; o < 1024; o += 256) {
                int c = o >> 4, x = o & 15;
                const float* u = U0 + x * K0;
                float acc = 0.f;
                #pragma unroll
                for (int k = 0; k < K0; ++k) acc += u[k] * w0[k * NCHAN + c];
                W0f[c * 16 + x] = acc;
            }
        }
    }
}

// ---------------------------------------------------------------------------
// global -> LDS async copy, 16 B per lane (dest = wave-uniform base + lane*16)
// ---------------------------------------------------------------------------
__device__ __forceinline__ void gload_lds16(const void* g, void* l) {
    __builtin_amdgcn_global_load_lds(
        (const __attribute__((address_space(1))) unsigned int*)g,
        (__attribute__((address_space(3))) unsigned int*)l, 16, 0, 0);
}

// ---------------------------------------------------------------------------
// Per-tile math (verified MFMA structure, unchanged except sy split in two
// independent accumulators to halve the serial FMA chain):
//   A[y][k]: k<16 -> W2bf[c][x*16+y][k]; k=16 -> bf16(C1[x,y]); else 0
//   B[k][a]: k<16 -> bf16(f[a][k]);      k=16 -> 1.0;           else 0
//   D[y][a] = M[x,y] (= A2 + C1);  lane (q,m) owns atom m, y-rows q*4..q*4+3.
//   s = sum_y f[y]*(sum_x f[x]*M[x,y] + C0[y]), reduced over q by 2 shfl_xor.
// ---------------------------------------------------------------------------
__device__ __forceinline__ float compute_tile(
    const bf16x8 (&aw)[16], float4 c0, int q,
    float4 va, float4 vb, float4 vc, float4 vd)
{
    float f0 = va.x, f1 = va.y, f2 = va.z, f3 = va.w;
    float f4 = vb.x, f5 = vb.y, f6 = vb.z, f7 = vb.w;
    float f8 = vc.x, f9 = vc.y, f10 = vc.z, f11 = vc.w;
    float f12 = vd.x, f13 = vd.y, f14 = vd.z, f15 = vd.w;

    unsigned pk0, pk1, pk2, pk3, pk4, pk5, pk6, pk7;
    asm("v_cvt_pk_bf16_f32 %0, %1, %2" : "=v"(pk0) : "v"(f0),  "v"(f1));
    asm("v_cvt_pk_bf16_f32 %0, %1, %2" : "=v"(pk1) : "v"(f2),  "v"(f3));
    asm("v_cvt_pk_bf16_f32 %0, %1, %2" : "=v"(pk2) : "v"(f4),  "v"(f5));
    asm("v_cvt_pk_bf16_f32 %0, %1, %2" : "=v"(pk3) : "v"(f6),  "v"(f7));
    asm("v_cvt_pk_bf16_f32 %0, %1, %2" : "=v"(pk4) : "v"(f8),  "v"(f9));
    asm("v_cvt_pk_bf16_f32 %0, %1, %2" : "=v"(pk5) : "v"(f10), "v"(f11));
    asm("v_cvt_pk_bf16_f32 %0, %1, %2" : "=v"(pk6) : "v"(f12), "v"(f13));
    asm("v_cvt_pk_bf16_f32 %0, %1, %2" : "=v"(pk7) : "v"(f14), "v"(f15));

    unsigned w0s = (q == 0) ? pk0 : (q == 1) ? pk4 : (q == 2) ? 0x00003f80u : 0u;
    unsigned w1s = (q == 0) ? pk1 : (q == 1) ? pk5 : 0u;
    unsigned w2s_ = (q == 0) ? pk2 : (q == 1) ? pk6 : 0u;
    unsigned w3s = (q == 0) ? pk3 : (q == 1) ? pk7 : 0u;
    u32x4 bu = {w0s, w1s, w2s_, w3s};
    bf16x8 bfr = __builtin_bit_cast(bf16x8, bu);

    const f32x4 z = {0.f, 0.f, 0.f, 0.f};
    f32x4 syA = z, syB = z;
    f32x4 d0 = __builtin_amdgcn_mfma_f32_16x16x32_bf16(aw[0], bfr, z, 0, 0, 0);
    f32x4 d1 = __builtin_amdgcn_mfma_f32_16x16x32_bf16(aw[1], bfr, z, 0, 0, 0);
    f32x4 d2 = __builtin_amdgcn_mfma_f32_16x16x32_bf16(aw[2], bfr, z, 0, 0, 0);
    f32x4 d3 = __builtin_amdgcn_mfma_f32_16x16x32_bf16(aw[3], bfr, z, 0, 0, 0);
    syA += d0 * f0;  d0 = __builtin_amdgcn_mfma_f32_16x16x32_bf16(aw[4],  bfr, z, 0, 0, 0);
    syB += d1 * f1;  d1 = __builtin_amdgcn_mfma_f32_16x16x32_bf16(aw[5],  bfr, z, 0, 0, 0);
    syA += d2 * f2;  d2 = __builtin_amdgcn_mfma_f32_16x16x32_bf16(aw[6],  bfr, z, 0, 0, 0);
    syB += d3 * f3;  d3 = __builtin_amdgcn_mfma_f32_16x16x32_bf16(aw[7],  bfr, z, 0, 0, 0);
    syA += d0 * f4;  d0 = __builtin_amdgcn_mfma_f32_16x16x32_bf16(aw[8],  bfr, z, 0, 0, 0);
    syB += d1 * f5;  d1 = __builtin_amdgcn_mfma_f32_16x16x32_bf16(aw[9],  bfr, z, 0, 0, 0);
    syA += d2 * f6;  d2 = __builtin_amdgcn_mfma_f32_16x16x32_bf16(aw[10], bfr, z, 0, 0, 0);
    syB += d3 * f7;  d3 = __builtin_amdgcn_mfma_f32_16x16x32_bf16(aw[11], bfr, z, 0, 0, 0);
    syA += d0 * f8;  d0 = __builtin_amdgcn_mfma_f32_16x16x32_bf16(aw[12], bfr, z, 0, 0, 0);
    syB += d1 * f9;  d1 = __builtin_amdgcn_mfma_f32_16x16x32_bf16(aw[13], bfr, z, 0, 0, 0);
    syA += d2 * f10; d2 = __builtin_amdgcn_mfma_f32_16x16x32_bf16(aw[14], bfr, z, 0, 0, 0);
    syB += d3 * f11; d3 = __builtin_amdgcn_mfma_f32_16x16x32_bf16(aw[15], bfr, z, 0, 0, 0);
    syA += d0 * f12; syB += d1 * f13; syA += d2 * f14; syB += d3 * f15;
    f32x4 sy = syA + syB;

    float t0 = (q & 1) ? f4 : f0;   float u0 = (q & 1) ? f12 : f8;
    float fy0 = (q & 2) ? u0 : t0;
    float t1 = (q & 1) ? f5 : f1;   float u1 = (q & 1) ? f13 : f9;
    float fy1 = (q & 2) ? u1 : t1;
    float t2 = (q & 1) ? f6 : f2;   float u2 = (q & 1) ? f14 : f10;
    float fy2 = (q & 2) ? u2 : t2;
    float t3 = (q & 1) ? f7 : f3;   float u3 = (q & 1) ? f15 : f11;
    float fy3 = (q & 2) ? u3 : t3;

    float s = fy0 * (sy.x + c0.x);
    s = fmaf(fy1, sy.y + c0.y, s);
    s = fmaf(fy2, sy.z + c0.z, s);
    s = fmaf(fy3, sy.w + c0.w, s);
    s += __shfl_xor(s, 16);
    s += __shfl_xor(s, 32);
    return s;
}

// ---------------------------------------------------------------------------
// Kernel 2: fused contraction, 4 waves / 4 channels per block, depth-3
// pipelined LDS staging.
//   grid = (16 c-groups, 125 atom chunks) = 2000 blocks; block = 256 thr.
//   Per tile: 16 atoms x 256 B (4-channel slab, contiguous in nf) staged by
//   ONE global_load_lds_dwordx4 per wave (linear LDS dest; inverse-XOR-
//   swizzled global source, T21 both-sides rule).  4 buffers, stage issued
//   DEPTH=3 tiles ahead, exact counted s_waitcnt vmcnt(3/2/1/0) before each
//   barrier so 3 stages stay in flight.  Outputs accumulate in registers;
//   stores once at the end.
//   Read: lane (q,m) reads atom m's 16 floats at byte
//   m*256 + ((wave*64 + r*16) ^ (m<<4)) -> 16 distinct 16B slots per quarter
//   (m vs m+8 2-way alias accepted, ~4 cyc/read).
// ---------------------------------------------------------------------------
__global__ __launch_bounds__(256, 3) void contract_kernel(
    const float* __restrict__ nf,   // [N, 64, 16]
    const void* __restrict__ wsv,
    float* __restrict__ out)        // [N, 64]
{
    __shared__ __align__(16) float fs[4][1024];   // 4 x 4 KB tile buffers

    const short* W2g = (const short*)wsv;
    const short* W1g = (const short*)((const char*)wsv + W1_BYTE_OFF);
    const float* W0g = (const float*)((const char*)wsv + W0_BYTE_OFF);

    const int tid  = threadIdx.x;
    const int wave = tid >> 6;      // 0..3 = channel-within-group
    const int lane = tid & 63;
    const int m    = lane & 15;     // atom-within-tile
    const int q    = lane >> 4;
    const int c    = blockIdx.x * 4 + wave;
    const int chunk = blockIdx.y;   // atoms [chunk*160, chunk*160+160)

    // --- staging addresses: lane stages 16B of atom a_st ---
    const int a_st = tid >> 4;                       // 0..15
    const int o_l  = (tid & 15) << 4;                // LDS slot within atom row
    const int o_g  = o_l ^ (a_st << 4);              // inverse swizzle (bijective)
    const char* sbase = (const char*)nf
        + ((size_t)(chunk * 160 + a_st) << 12)       // atom * 4096 B
        + ((size_t)blockIdx.x << 8)                  // channel-group * 256 B
        + o_g;
    const unsigned ldw = (unsigned)(wave << 10);     // wave-uniform LDS dest off

    // --- A-operand fragments (W2 + C1 in K-slot 16), resident in VGPRs ---
    bf16x8 aw[16];
    #pragma unroll
    for (int j = 0; j < 16; ++j) {
        bf16x8 v = (bf16x8)0;
        if (q < 2) {
            v = *(const bf16x8*)(W2g + ((size_t)c << 12) + ((j * 16 + m) << 4) + (q << 3));
        } else if (q == 2) {
            v[0] = W1g[(c << 8) + (j << 4) + m];
        }
        aw[j] = v;
    }
    const float4 c0 = *(const float4*)(W0g + (c << 4) + (q << 2));

    // --- LDS read offsets (swizzled) ---
    const unsigned sw = (unsigned)(m << 4);
    const unsigned zb = (unsigned)(wave << 6);

    float outv[NT];

    // prologue: stage tiles 0..DEPTH-1
    #pragma unroll
    for (int t = 0; t < DEPTH; ++t)
        gload_lds16(sbase + (size_t)t * 65536, (char*)&fs[t][0] + ldw);

    #pragma unroll
    for (int T = 0; T < NT; ++T) {
        if (T + DEPTH < NT)
            gload_lds16(sbase + (size_t)(T + DEPTH) * 65536,
                        (char*)&fs[(T + DEPTH) & 3][0] + ldw);
        const int wcnt = (NT - 1 - T < DEPTH) ? (NT - 1 - T) : DEPTH;
        if      (wcnt == 3) asm volatile("s_waitcnt vmcnt(3)" ::: "memory");
        else if (wcnt == 2) asm volatile("s_waitcnt vmcnt(2)" ::: "memory");
        else if (wcnt == 1) asm volatile("s_waitcnt vmcnt(1)" ::: "memory");
        else                asm volatile("s_waitcnt vmcnt(0)" ::: "memory");
        __builtin_amdgcn_s_barrier();
        __builtin_amdgcn_sched_barrier(0);

        const char* lrb = (const char*)&fs[T & 3][0] + (m << 8);
        float4 va = *(const float4*)(lrb + ((zb +  0) ^ sw));
        float4 vb = *(const float4*)(lrb + ((zb + 16) ^ sw));
        float4 vc = *(const float4*)(lrb + ((zb + 32) ^ sw));
        float4 vd = *(const float4*)(lrb + ((zb + 48) ^ sw));

        outv[T] = compute_tile(aw, c0, q, va, vb, vc, vd);

        __builtin_amdgcn_s_barrier();   // readers done before buffer reuse
    }

    if (q == 0) {
        float* ob = out + ((size_t)(chunk * 160 + m)) * 64 + c;
        #pragma unroll
        for (int T = 0; T < NT; ++T)
            ob[(size_t)T * 1024] = outv[T];   // atom += 16 -> +1024 floats
    }
}

extern "C" void kernel_launch(void* const* d_in, const int* in_sizes, int n_in,
                              void* d_out, int out_size, void* d_ws, size_t ws_size,
                              hipStream_t stream)
{
    const float* nf = (const float*)d_in[0];
    const float* U2 = (const float*)d_in[1];
    const float* U1 = (const float*)d_in[2];
    const float* U0 = (const float*)d_in[3];
    const float* w2 = (const float*)d_in[4];
    const float* w1 = (const float*)d_in[5];
    const float* w0 = (const float*)d_in[6];
    float* out = (float*)d_out;

    precompute_kernel<<<264, 256, 0, stream>>>(U2, U1, U0, w2, w1, w0, d_ws);

    dim3 grid(16, 125);   // x = channel group of 4, y = atom chunk of 160
    contract_kernel<<<grid, 256, 0, stream>>>(nf, d_ws, out);
}